// Round 5
// baseline (134.861 us; speedup 1.0000x reference)
//
#include <hip/hip_runtime.h>

#define N 4096
#define NBJ 64          // j-chunks; partials = NBJ*N*8B = 2 MB in d_ws
#define EPS 1e-8f

typedef unsigned long long u64;

// ---------------------------------------------------------------------------
// Single fused kernel. grid = (16, NBJ), block = 256.
// Phase 1: block (ib,jb) accumulates repulsive partial for i in
//   [ib*256, +256) over j in [jb*64, +64) (j-tile in LDS), writes part[jb][i].
// Ticket: device fence + atomicAdd(cnt[ib]); 63 of 64 blocks exit.
// Phase 2 (last block per ib): reduces the 64 partials per i with
//   agent-scope loads, redundantly reduces agent 0's column (no cross-group
//   dependency), then attraction + propagation + cost. Deadlock-free: no
//   spinning, no co-residency assumption.
// ---------------------------------------------------------------------------
__global__ __launch_bounds__(256) void social_force(
    const float4* __restrict__ state4,
    const float*  __restrict__ cost_in,
    const float*  __restrict__ goals,
    const float*  __restrict__ rip,
    const float4* __restrict__ obs4,
    int*          __restrict__ cnt,     // [16], pre-zeroed via hipMemsetAsync
    float2*       __restrict__ part,    // [NBJ][N]
    float*        __restrict__ out)
{
    __shared__ float2 sj[64];
    __shared__ int    s_last;
    __shared__ float2 s_p0;

    const int tid = threadIdx.x;
    const int ib  = blockIdx.x;              // 0..15
    const int jb  = blockIdx.y;              // 0..NBJ-1
    const int i   = ib * 256 + tid;

    if (tid < 64) {
        const float4 s = state4[jb * 64 + tid];
        sj[tid] = make_float2(s.x, s.y);
    }
    const float4 si = state4[i];
    const float xi = si.x, yi = si.y;
    __syncthreads();

    // mag/dist = ALPHA * exp((2R - d)/BETTA) / d = exp2(C0 - C1*d) / d
    const float C1 = 1.44269504088896340736f / 0.71f;   // log2e / BETTA
    const float C0 = 0.6f * C1 + 3.41414351f;           // 2R*C1 + log2(ALPHA)

    float fx0 = 0.f, fy0 = 0.f, fx1 = 0.f, fy1 = 0.f;
#pragma unroll 8
    for (int jj = 0; jj < 64; jj += 2) {
        {
            const float2 pj = sj[jj];
            const float dx   = xi - pj.x;
            const float dy   = yi - pj.y;
            const float r2   = fmaf(dx, dx, fmaf(dy, dy, EPS));
            const float inv  = __builtin_amdgcn_rsqf(r2);
            const float d    = r2 * inv;
            const float coef = __builtin_amdgcn_exp2f(fmaf(d, -C1, C0)) * inv;
            fx0 = fmaf(coef, dx, fx0);   // i==j: dx=dy=0 -> exact 0, matches eye-mask
            fy0 = fmaf(coef, dy, fy0);
        }
        {
            const float2 pj = sj[jj + 1];
            const float dx   = xi - pj.x;
            const float dy   = yi - pj.y;
            const float r2   = fmaf(dx, dx, fmaf(dy, dy, EPS));
            const float inv  = __builtin_amdgcn_rsqf(r2);
            const float d    = r2 * inv;
            const float coef = __builtin_amdgcn_exp2f(fmaf(d, -C1, C0)) * inv;
            fx1 = fmaf(coef, dx, fx1);
            fy1 = fmaf(coef, dy, fy1);
        }
    }
    part[(size_t)jb * N + i] = make_float2(fx0 + fx1, fy0 + fy1);

    // ---- ticket: last block of this ib-group finalizes -------------------
    __threadfence();                               // release partials
    if (tid == 0)
        s_last = (atomicAdd(&cnt[ib], 1) == NBJ - 1) ? 1 : 0;
    __syncthreads();
    if (!s_last) return;
    __threadfence();                               // acquire

    const u64* pp = (const u64*)part;

    // reduce column i over all 64 j-chunks (agent-scope loads: bypass L1,
    // coherent with other XCDs' flushed writes)
    float Fx = 0.f, Fy = 0.f;
    for (int k = 0; k < NBJ; ++k) {
        const u64 raw = __hip_atomic_load(pp + (size_t)k * N + i,
                                          __ATOMIC_RELAXED, __HIP_MEMORY_SCOPE_AGENT);
        const float2 p = __builtin_bit_cast(float2, raw);
        Fx += p.x; Fy += p.y;
    }

    // agent 0's new pose (needed by every cost row) — redundantly per group:
    // lane k of wave 0 loads part[k][0], 64-lane shuffle reduce, propagate.
    if (tid < 64) {
        const u64 raw = __hip_atomic_load(pp + (size_t)tid * N,
                                          __ATOMIC_RELAXED, __HIP_MEMORY_SCOPE_AGENT);
        float2 f0 = __builtin_bit_cast(float2, raw);
#pragma unroll
        for (int off = 32; off > 0; off >>= 1) {
            f0.x += __shfl_down(f0.x, off);
            f0.y += __shfl_down(f0.y, off);
        }
        if (tid == 0) {
            const float4 s0 = state4[0];
            const float gx = goals[0] - s0.x, gy = goals[1] - s0.y;
            const float gd = sqrtf(fmaf(gx, gx, fmaf(gy, gy, EPS)));
            const float Fx0 = f0.x + 120.f * (1.34f * gx / gd - s0.z);  // K*MASS=120
            const float Fy0 = f0.y + 120.f * (1.34f * gy / gd - s0.w);
            float vnx = fmaf(Fx0, 0.4f / 60.f, s0.z);
            float vny = fmaf(Fy0, 0.4f / 60.f, s0.w);
            const float sp  = sqrtf(fmaf(vnx, vnx, fmaf(vny, vny, EPS)));
            const float fac = fminf(1.f, 1.34f / sp);
            vnx *= fac; vny *= fac;
            s_p0 = make_float2(fmaf(vnx, 0.4f, s0.x), fmaf(vny, 0.4f, s0.y));
        }
    }
    __syncthreads();

    // attraction + propagation for agent i
    const float px = si.x, py = si.y, vx = si.z, vy = si.w;
    const float gx = goals[i * 2 + 0] - px, gy = goals[i * 2 + 1] - py;
    const float gd = sqrtf(fmaf(gx, gx, fmaf(gy, gy, EPS)));
    Fx += 120.f * (1.34f * gx / gd - vx);
    Fy += 120.f * (1.34f * gy / gd - vy);
    float vnx = fmaf(Fx, 0.4f / 60.f, vx);
    float vny = fmaf(Fy, 0.4f / 60.f, vy);
    const float sp  = sqrtf(fmaf(vnx, vnx, fmaf(vny, vny, EPS)));
    const float fac = fminf(1.f, 1.34f / sp);
    vnx *= fac; vny *= fac;
    const float pnx = fmaf(vnx, 0.4f, px);
    const float pny = fmaf(vny, 0.4f, py);

    out[i * 4 + 0] = pnx;
    out[i * 4 + 1] = pny;
    out[i * 4 + 2] = vnx;
    out[i * 4 + 3] = vny;

    // cost = cost_in - pg + blame + dev
    const float rx = rip[0], ry = rip[1];
    const float gvx = goals[0] - rx, gvy = goals[1] - ry;
    const float p0x = s_p0.x, p0y = s_p0.y;
    const float pg = ((p0x - rx) * gvx + (p0y - ry) * gvy)
                   / (sqrtf(gvx * gvx + gvy * gvy) + EPS);
    const float ddx = pnx - p0x, ddy = pny - p0y;
    const float dist_rp = sqrtf(fmaf(ddx, ddx, fmaf(ddy, ddy, EPS)));
    const float blame = __expf(-dist_rp);
    const float4 ob = obs4[i];
    const float dev = (pnx - ob.x) * (pnx - ob.x) + (pny - ob.y) * (pny - ob.y);

    out[4 * N + i] = cost_in[i] + (-pg + blame + dev);
}

extern "C" void kernel_launch(void* const* d_in, const int* in_sizes, int n_in,
                              void* d_out, int out_size, void* d_ws, size_t ws_size,
                              hipStream_t stream) {
    const float* state = (const float*)d_in[0];
    const float* cost  = (const float*)d_in[1];
    const float* goals = (const float*)d_in[2];
    const float* rip   = (const float*)d_in[3];
    const float* obs   = (const float*)d_in[4];
    float* out   = (float*)d_out;

    int*    cnt  = (int*)d_ws;                         // 16 counters
    float2* part = (float2*)((char*)d_ws + 256);       // 2 MB partials

    hipMemsetAsync(d_ws, 0, 256, stream);              // zero tickets (capturable)
    social_force<<<dim3(16, NBJ), 256, 0, stream>>>(
        (const float4*)state, cost, goals, rip, (const float4*)obs,
        cnt, part, out);
}

// Round 6
// 76.360 us; speedup vs baseline: 1.7661x; 1.7661x over previous
//
#include <hip/hip_runtime.h>

#define N 4096
#define IPB 8           // agents finalized per block; grid = N/IPB = 512 blocks
#define EPS 1e-8f

// ---------------------------------------------------------------------------
// Fully fused, intra-block only (no cross-block reduction, no fences).
// grid = 512, block = 256. Block b owns agents i in [b*8, b*8+8).
//   - stage all N positions in LDS (32 KB)
//   - 32 threads per agent, thread js covers j = js, js+32, ... (128 pairs);
//     stride-32 -> 2-way LDS bank aliasing only (free, m136)
//   - every block redundantly computes agent 0's full repulsion (16 j per
//     thread over all 256 threads) so cost needs no cross-block data;
//     identical code+data per block -> bit-identical p0 everywhere
//   - width-32 shuffle reduce per agent, wave reduce for agent 0, epilogue
//     (attraction, propagation, cost) on threads 0..7.
// ---------------------------------------------------------------------------
__global__ __launch_bounds__(256) void social_fused(
    const float2* __restrict__ state2,   // [2i]=(x,y), [2i+1]=(vx,vy)
    const float*  __restrict__ cost_in,
    const float*  __restrict__ goals,
    const float*  __restrict__ rip,
    const float4* __restrict__ obs4,
    float*        __restrict__ out)
{
    __shared__ float2 sj[N];        // 32 KB positions
    __shared__ float2 s_red[IPB];
    __shared__ float2 s_f0[4];
    __shared__ float2 s_p0;

    const int tid = threadIdx.x;
    const int is  = tid >> 5;       // 0..7  (agent slot)
    const int js  = tid & 31;       // 0..31 (j-slice)
    const int i   = blockIdx.x * IPB + is;

    for (int k = tid; k < N; k += 256)
        sj[k] = state2[2 * k];
    __syncthreads();

    // coef(d) = ALPHA*exp((2R-d)/BETTA)/d = exp2(C0 - C1*d)/d
    const float C1 = 1.44269504088896340736f / 0.71f;   // log2e/BETTA
    const float C0 = 0.6f * C1 + 3.41414351f;           // 2R*C1 + log2(ALPHA)

    const float2 pi = sj[i];
    float fxa[4] = {0.f, 0.f, 0.f, 0.f};
    float fya[4] = {0.f, 0.f, 0.f, 0.f};

    for (int jj = 0; jj < 128; jj += 4) {
#pragma unroll
        for (int u = 0; u < 4; ++u) {
            const float2 pj = sj[js + 32 * (jj + u)];
            const float dx   = pi.x - pj.x;
            const float dy   = pi.y - pj.y;
            const float r2   = fmaf(dx, dx, fmaf(dy, dy, EPS));
            const float inv  = __builtin_amdgcn_rsqf(r2);
            const float d    = r2 * inv;
            const float coef = __builtin_amdgcn_exp2f(fmaf(d, -C1, C0)) * inv;
            fxa[u] = fmaf(coef, dx, fxa[u]);   // i==j: dx=dy=0 -> exact 0
            fya[u] = fmaf(coef, dy, fya[u]);
        }
    }
    float fx = (fxa[0] + fxa[1]) + (fxa[2] + fxa[3]);
    float fy = (fya[0] + fya[1]) + (fya[2] + fya[3]);

    // redundant agent-0 repulsion: thread t covers j = t, t+256, ..., t+3840
    const float2 p0pos = sj[0];
    float f0x = 0.f, f0y = 0.f;
#pragma unroll 4
    for (int k = 0; k < 16; ++k) {
        const float2 pj = sj[tid + 256 * k];
        const float dx   = p0pos.x - pj.x;
        const float dy   = p0pos.y - pj.y;
        const float r2   = fmaf(dx, dx, fmaf(dy, dy, EPS));
        const float inv  = __builtin_amdgcn_rsqf(r2);
        const float d    = r2 * inv;
        const float coef = __builtin_amdgcn_exp2f(fmaf(d, -C1, C0)) * inv;
        f0x = fmaf(coef, dx, f0x);
        f0y = fmaf(coef, dy, f0y);
    }

    // per-agent width-32 shuffle reduce
#pragma unroll
    for (int off = 16; off > 0; off >>= 1) {
        fx += __shfl_down(fx, off, 32);
        fy += __shfl_down(fy, off, 32);
    }
    if (js == 0) s_red[is] = make_float2(fx, fy);

    // agent-0 wave reduce (width 64), 4 wave partials to LDS
#pragma unroll
    for (int off = 32; off > 0; off >>= 1) {
        f0x += __shfl_down(f0x, off, 64);
        f0y += __shfl_down(f0y, off, 64);
    }
    if ((tid & 63) == 0) s_f0[tid >> 6] = make_float2(f0x, f0y);
    __syncthreads();

    if (tid == 0) {
        const float F0rx = (s_f0[0].x + s_f0[1].x) + (s_f0[2].x + s_f0[3].x);
        const float F0ry = (s_f0[0].y + s_f0[1].y) + (s_f0[2].y + s_f0[3].y);
        const float2 p0 = sj[0];
        const float2 v0 = state2[1];
        const float gx = goals[0] - p0.x, gy = goals[1] - p0.y;
        const float gd = sqrtf(fmaf(gx, gx, fmaf(gy, gy, EPS)));
        const float Fx0 = F0rx + 120.f * (1.34f * gx / gd - v0.x);   // K*MASS=120
        const float Fy0 = F0ry + 120.f * (1.34f * gy / gd - v0.y);
        float vnx = fmaf(Fx0, 0.4f / 60.f, v0.x);
        float vny = fmaf(Fy0, 0.4f / 60.f, v0.y);
        const float sp  = sqrtf(fmaf(vnx, vnx, fmaf(vny, vny, EPS)));
        const float fac = fminf(1.f, 1.34f / sp);
        vnx *= fac; vny *= fac;
        s_p0 = make_float2(fmaf(vnx, 0.4f, p0.x), fmaf(vny, 0.4f, p0.y));
    }
    __syncthreads();

    if (tid < IPB) {
        const int ia = blockIdx.x * IPB + tid;
        float Fx = s_red[tid].x, Fy = s_red[tid].y;

        const float2 pp = state2[2 * ia];
        const float2 vv = state2[2 * ia + 1];
        const float gx = goals[ia * 2 + 0] - pp.x, gy = goals[ia * 2 + 1] - pp.y;
        const float gd = sqrtf(fmaf(gx, gx, fmaf(gy, gy, EPS)));
        Fx += 120.f * (1.34f * gx / gd - vv.x);
        Fy += 120.f * (1.34f * gy / gd - vv.y);
        float vnx = fmaf(Fx, 0.4f / 60.f, vv.x);
        float vny = fmaf(Fy, 0.4f / 60.f, vv.y);
        const float sp  = sqrtf(fmaf(vnx, vnx, fmaf(vny, vny, EPS)));
        const float fac = fminf(1.f, 1.34f / sp);
        vnx *= fac; vny *= fac;
        const float pnx = fmaf(vnx, 0.4f, pp.x);
        const float pny = fmaf(vny, 0.4f, pp.y);

        ((float4*)out)[ia] = make_float4(pnx, pny, vnx, vny);

        // cost = cost_in - pg + blame + dev
        const float rx = rip[0], ry = rip[1];
        const float gvx = goals[0] - rx, gvy = goals[1] - ry;
        const float pg = ((s_p0.x - rx) * gvx + (s_p0.y - ry) * gvy)
                       / (sqrtf(gvx * gvx + gvy * gvy) + EPS);
        const float ddx = pnx - s_p0.x, ddy = pny - s_p0.y;
        const float dist_rp = sqrtf(fmaf(ddx, ddx, fmaf(ddy, ddy, EPS)));
        const float blame = __expf(-dist_rp);
        const float4 ob = obs4[ia];
        const float dev = (pnx - ob.x) * (pnx - ob.x) + (pny - ob.y) * (pny - ob.y);

        out[4 * N + ia] = cost_in[ia] + (-pg + blame + dev);
    }
}

extern "C" void kernel_launch(void* const* d_in, const int* in_sizes, int n_in,
                              void* d_out, int out_size, void* d_ws, size_t ws_size,
                              hipStream_t stream) {
    const float* state = (const float*)d_in[0];
    const float* cost  = (const float*)d_in[1];
    const float* goals = (const float*)d_in[2];
    const float* rip   = (const float*)d_in[3];
    const float* obs   = (const float*)d_in[4];
    float* out = (float*)d_out;

    social_fused<<<N / IPB, 256, 0, stream>>>(
        (const float2*)state, cost, goals, rip, (const float4*)obs, out);
}

// Round 7
// 69.386 us; speedup vs baseline: 1.9436x; 1.1005x over previous
//
#include <hip/hip_runtime.h>

#define N 4096
#define NBJ 64          // j-chunks; partials = NBJ*N*8B = 2 MB in d_ws
#define EPS 1e-8f

typedef float v2f __attribute__((ext_vector_type(2)));

// ---------------------------------------------------------------------------
// Kernel 1: partial repulsive forces, SoA j-tile + packed-f32 (v_pk_*) math.
// grid = (16, NBJ) = 1024 blocks (4 waves/SIMD), 256 threads.
// Thread (i, jb) accumulates i's force over 64 j's; LDS reads are wave-
// broadcast (identical address on all lanes -> conflict-free). Two j's per
// iteration through float2 vector arithmetic -> compiler can emit
// v_pk_fma_f32 / v_pk_mul_f32, halving non-transcendental VALU issue.
// ---------------------------------------------------------------------------
__global__ __launch_bounds__(256) void rep_pairs(const float4* __restrict__ state4,
                                                 float2* __restrict__ part) {
    __shared__ float sx[64];
    __shared__ float sy[64];
    const int tid = threadIdx.x;
    const int jb  = blockIdx.y;
    const int i   = blockIdx.x * 256 + tid;

    if (tid < 64) {
        const float4 s = state4[jb * 64 + tid];
        sx[tid] = s.x;
        sy[tid] = s.y;
    }
    const float4 si = state4[i];
    __syncthreads();

    // coef(d) = ALPHA*exp((2R-d)/BETTA)/d = exp2(C0 - C1*d)/d
    const float C1 = 1.44269504088896340736f / 0.71f;   // log2e/BETTA
    const float C0 = 0.6f * C1 + 3.41414351f;           // 2R*C1 + log2(ALPHA)

    const v2f xi  = {si.x, si.x};
    const v2f yi  = {si.y, si.y};
    const v2f eps = {EPS, EPS};
    v2f fx0 = {0.f, 0.f}, fy0 = {0.f, 0.f};
    v2f fx1 = {0.f, 0.f}, fy1 = {0.f, 0.f};

#pragma unroll 8
    for (int jj = 0; jj < 64; jj += 4) {
        {   // pairs jj, jj+1
            const v2f X = *(const v2f*)&sx[jj];
            const v2f Y = *(const v2f*)&sy[jj];
            const v2f dx = xi - X;
            const v2f dy = yi - Y;
            const v2f r2 = dx * dx + (dy * dy + eps);
            v2f inv; inv.x = __builtin_amdgcn_rsqf(r2.x);
                     inv.y = __builtin_amdgcn_rsqf(r2.y);
            const v2f d   = r2 * inv;
            const v2f arg = C0 - C1 * d;
            v2f e; e.x = __builtin_amdgcn_exp2f(arg.x);
                   e.y = __builtin_amdgcn_exp2f(arg.y);
            const v2f coef = e * inv;
            fx0 += coef * dx;   // i==j: dx=dy=0 -> exact 0, matches eye-mask
            fy0 += coef * dy;
        }
        {   // pairs jj+2, jj+3
            const v2f X = *(const v2f*)&sx[jj + 2];
            const v2f Y = *(const v2f*)&sy[jj + 2];
            const v2f dx = xi - X;
            const v2f dy = yi - Y;
            const v2f r2 = dx * dx + (dy * dy + eps);
            v2f inv; inv.x = __builtin_amdgcn_rsqf(r2.x);
                     inv.y = __builtin_amdgcn_rsqf(r2.y);
            const v2f d   = r2 * inv;
            const v2f arg = C0 - C1 * d;
            v2f e; e.x = __builtin_amdgcn_exp2f(arg.x);
                   e.y = __builtin_amdgcn_exp2f(arg.y);
            const v2f coef = e * inv;
            fx1 += coef * dx;
            fy1 += coef * dy;
        }
    }
    const v2f fxs = fx0 + fx1, fys = fy0 + fy1;
    part[(size_t)jb * N + i] = make_float2(fxs.x + fxs.y, fys.x + fys.y);
}

// ---------------------------------------------------------------------------
// Kernel 2: reduce partials (float4: 2 agents/thread) + attraction +
// propagation + cost. grid = N/128 = 32 blocks, 256 threads:
// ip = tid&63 (agent pair), ks = tid>>6 (16 k's each). Wave 0 also
// shuffle-reduces agent 0's column -> s_p0 for the cost term.
// ---------------------------------------------------------------------------
__global__ __launch_bounds__(256) void finalize(const float4* __restrict__ state4,
                                                const float*  __restrict__ cost_in,
                                                const float*  __restrict__ goals,
                                                const float*  __restrict__ rip,
                                                const float4* __restrict__ obs4,
                                                const float2* __restrict__ part,
                                                float*        __restrict__ out) {
    __shared__ float4 red[4][64];
    __shared__ float2 s_p0;
    const int tid = threadIdx.x;
    const int ip  = tid & 63;
    const int ks  = tid >> 6;                 // 0..3
    const int i0  = blockIdx.x * 128 + ip * 2;
    const float4* p4 = (const float4*)part;   // [k][N/2]

    float4 acc = make_float4(0.f, 0.f, 0.f, 0.f);
    for (int k = ks * 16; k < ks * 16 + 16; ++k) {
        const float4 p = p4[(size_t)k * (N / 2) + (i0 >> 1)];
        acc.x += p.x; acc.y += p.y; acc.z += p.z; acc.w += p.w;
    }
    red[ks][ip] = acc;

    // wave 0: agent 0's 64 partials across 64 lanes -> propagate to s_p0
    if (tid < 64) {
        float2 f0 = part[(size_t)tid * N];
#pragma unroll
        for (int off = 32; off > 0; off >>= 1) {
            f0.x += __shfl_down(f0.x, off);
            f0.y += __shfl_down(f0.y, off);
        }
        if (tid == 0) {
            const float4 s0 = state4[0];
            const float gx = goals[0] - s0.x, gy = goals[1] - s0.y;
            const float gd = sqrtf(fmaf(gx, gx, fmaf(gy, gy, EPS)));
            const float Fx0 = f0.x + 120.f * (1.34f * gx / gd - s0.z);  // K*MASS=120
            const float Fy0 = f0.y + 120.f * (1.34f * gy / gd - s0.w);
            float vnx = fmaf(Fx0, 0.4f / 60.f, s0.z);
            float vny = fmaf(Fy0, 0.4f / 60.f, s0.w);
            const float sp  = sqrtf(fmaf(vnx, vnx, fmaf(vny, vny, EPS)));
            const float fac = fminf(1.f, 1.34f / sp);
            vnx *= fac; vny *= fac;
            s_p0 = make_float2(fmaf(vnx, 0.4f, s0.x), fmaf(vny, 0.4f, s0.y));
        }
    }
    __syncthreads();

    if (ks == 0) {
        float4 a = red[0][ip];
        const float4 b = red[1][ip], c = red[2][ip], d4 = red[3][ip];
        a.x += b.x + c.x + d4.x;
        a.y += b.y + c.y + d4.y;
        a.z += b.z + c.z + d4.z;
        a.w += b.w + c.w + d4.w;

        const float4 g2 = ((const float4*)goals)[i0 >> 1];   // (g0x,g0y,g1x,g1y)
        const float2 ci = ((const float2*)cost_in)[i0 >> 1];
        const float rx = rip[0], ry = rip[1];
        const float gvx = goals[0] - rx, gvy = goals[1] - ry;
        const float inv_gl = 1.f / (sqrtf(gvx * gvx + gvy * gvy) + EPS);
        const float p0x = s_p0.x, p0y = s_p0.y;
        const float pg = ((p0x - rx) * gvx + (p0y - ry) * gvy) * inv_gl;

        float2 cost_out;
#pragma unroll
        for (int u = 0; u < 2; ++u) {
            const int ia = i0 + u;
            float Fx = u ? a.z : a.x;
            float Fy = u ? a.w : a.y;
            const float4 s = state4[ia];
            const float gx = (u ? g2.z : g2.x) - s.x;
            const float gy = (u ? g2.w : g2.y) - s.y;
            const float gd = sqrtf(fmaf(gx, gx, fmaf(gy, gy, EPS)));
            Fx += 120.f * (1.34f * gx / gd - s.z);
            Fy += 120.f * (1.34f * gy / gd - s.w);
            float vnx = fmaf(Fx, 0.4f / 60.f, s.z);
            float vny = fmaf(Fy, 0.4f / 60.f, s.w);
            const float sp  = sqrtf(fmaf(vnx, vnx, fmaf(vny, vny, EPS)));
            const float fac = fminf(1.f, 1.34f / sp);
            vnx *= fac; vny *= fac;
            const float pnx = fmaf(vnx, 0.4f, s.x);
            const float pny = fmaf(vny, 0.4f, s.y);

            ((float4*)out)[ia] = make_float4(pnx, pny, vnx, vny);

            const float ddx = pnx - p0x, ddy = pny - p0y;
            const float dist_rp = sqrtf(fmaf(ddx, ddx, fmaf(ddy, ddy, EPS)));
            const float blame = __expf(-dist_rp);
            const float4 ob = obs4[ia];
            const float dev = (pnx - ob.x) * (pnx - ob.x) + (pny - ob.y) * (pny - ob.y);
            const float cv = (u ? ci.y : ci.x) + (-pg + blame + dev);
            if (u) cost_out.y = cv; else cost_out.x = cv;
        }
        ((float2*)(out + 4 * N))[i0 >> 1] = cost_out;
    }
}

extern "C" void kernel_launch(void* const* d_in, const int* in_sizes, int n_in,
                              void* d_out, int out_size, void* d_ws, size_t ws_size,
                              hipStream_t stream) {
    const float* state = (const float*)d_in[0];
    const float* cost  = (const float*)d_in[1];
    const float* goals = (const float*)d_in[2];
    const float* rip   = (const float*)d_in[3];
    const float* obs   = (const float*)d_in[4];
    float* out   = (float*)d_out;
    float2* part = (float2*)d_ws;   // 2 MB

    rep_pairs<<<dim3(16, NBJ), 256, 0, stream>>>((const float4*)state, part);
    finalize<<<N / 128, 256, 0, stream>>>((const float4*)state, cost, goals, rip,
                                          (const float4*)obs, part, out);
}